// Round 1
// baseline (519.494 us; speedup 1.0000x reference)
//
#include <hip/hip_runtime.h>
#include <math.h>

#define T_TOK 8192
#define NEXP  256
#define HD    7168

// ---------------- Router GEMM: logits[t][e] = sum_h X[t][h] * W[e][h] ----------------
// BM=128 tokens, BN=64 experts, BK=32, 256 threads, 8x4 per-thread tile.
#define BM 128
#define BN 64
#define BK 32
#define TM 8
#define TN 4

__global__ __launch_bounds__(256) void router_gemm(const float* __restrict__ X,
                                                   const float* __restrict__ W,
                                                   float* __restrict__ logits) {
    // LDS tiles stored K-major (transposed) so inner-loop reads are float4.
    // Pad +4 floats to keep 16B alignment of each row and rotate banks.
    __shared__ float As[BK][BM + 4];
    __shared__ float Bs[BK][BN + 4];

    const int tid = threadIdx.x;
    const int bx  = blockIdx.x;   // token tile 0..63
    const int by  = blockIdx.y;   // expert tile 0..3
    const int tx  = tid & 15;     // expert dir: 16 * TN(4) = 64
    const int ty  = tid >> 4;     // token  dir: 16 * TM(8) = 128
    const int row0 = bx * BM;
    const int col0 = by * BN;

    const int lr = tid >> 3;      // 0..31 staging row
    const int lc = tid & 7;       // 0..7  staging float4 col

    float acc[TM][TN];
#pragma unroll
    for (int i = 0; i < TM; ++i)
#pragma unroll
        for (int j = 0; j < TN; ++j) acc[i][j] = 0.f;

    for (int k0 = 0; k0 < HD; k0 += BK) {
        __syncthreads();
        // Stage A: 128 rows x 32 k  (4 passes of 32 rows)
#pragma unroll
        for (int p = 0; p < 4; ++p) {
            const int r = lr + p * 32;
            const float4 v = *(const float4*)(&X[(size_t)(row0 + r) * HD + k0 + lc * 4]);
            As[lc * 4 + 0][r] = v.x;
            As[lc * 4 + 1][r] = v.y;
            As[lc * 4 + 2][r] = v.z;
            As[lc * 4 + 3][r] = v.w;
        }
        // Stage B: 64 rows x 32 k  (2 passes of 32 rows)
#pragma unroll
        for (int p = 0; p < 2; ++p) {
            const int r = lr + p * 32;
            const float4 v = *(const float4*)(&W[(size_t)(col0 + r) * HD + k0 + lc * 4]);
            Bs[lc * 4 + 0][r] = v.x;
            Bs[lc * 4 + 1][r] = v.y;
            Bs[lc * 4 + 2][r] = v.z;
            Bs[lc * 4 + 3][r] = v.w;
        }
        __syncthreads();

#pragma unroll
        for (int kk = 0; kk < BK; ++kk) {
            float a[TM], b[TN];
            const float4 a0 = *(const float4*)(&As[kk][ty * TM + 0]);
            const float4 a1 = *(const float4*)(&As[kk][ty * TM + 4]);
            const float4 b0 = *(const float4*)(&Bs[kk][tx * TN]);
            a[0] = a0.x; a[1] = a0.y; a[2] = a0.z; a[3] = a0.w;
            a[4] = a1.x; a[5] = a1.y; a[6] = a1.z; a[7] = a1.w;
            b[0] = b0.x; b[1] = b0.y; b[2] = b0.z; b[3] = b0.w;
#pragma unroll
            for (int i = 0; i < TM; ++i)
#pragma unroll
                for (int j = 0; j < TN; ++j)
                    acc[i][j] = fmaf(a[i], b[j], acc[i][j]);
        }
    }

    // Epilogue: one float4 store per i.
#pragma unroll
    for (int i = 0; i < TM; ++i) {
        const int t = row0 + ty * TM + i;
        float4 v;
        v.x = acc[i][0]; v.y = acc[i][1]; v.z = acc[i][2]; v.w = acc[i][3];
        *(float4*)(&logits[(size_t)t * NEXP + col0 + tx * TN]) = v;
    }
}

// ---------------- Gating: one wave per token ----------------
// lane l owns experts 4l..4l+3; group g = l>>3 (8 lanes * 4 experts = 32/group).
__global__ __launch_bounds__(256) void gate_kernel(const float* __restrict__ logits,
                                                   const float* __restrict__ bias,
                                                   float* __restrict__ out_w,
                                                   float* __restrict__ out_e) {
    const int wave = threadIdx.x >> 6;
    const int lane = threadIdx.x & 63;
    const int t = blockIdx.x * 4 + wave;
    if (t >= T_TOK) return;

    const float4 lv = *(const float4*)(&logits[(size_t)t * NEXP + lane * 4]);
    const float4 bv = *(const float4*)(&bias[lane * 4]);

    float s[4], c[4];
    s[0] = 1.f / (1.f + expf(-lv.x));
    s[1] = 1.f / (1.f + expf(-lv.y));
    s[2] = 1.f / (1.f + expf(-lv.z));
    s[3] = 1.f / (1.f + expf(-lv.w));
    c[0] = s[0] + bv.x;
    c[1] = s[1] + bv.y;
    c[2] = s[2] + bv.z;
    c[3] = s[3] + bv.w;

    // ---- group score: sum of top-2 of scores_for_choice within group of 32 ----
    // lane-local top2 of c[0..3]
    float a = fmaxf(c[0], c[1]), b = fminf(c[0], c[1]);
    float d = fmaxf(c[2], c[3]), e = fminf(c[2], c[3]);
    float m1 = fmaxf(a, d);
    float m2 = fmaxf(fminf(a, d), fmaxf(b, e));
    // reduce across the 8 lanes of the group (xor 1,2,4 stays in-group)
#pragma unroll
    for (int off = 1; off < 8; off <<= 1) {
        const float o1 = __shfl_xor(m1, off);
        const float o2 = __shfl_xor(m2, off);
        const float n1 = fmaxf(m1, o1);
        const float n2 = fmaxf(fminf(m1, o1), fmaxf(m2, o2));
        m1 = n1; m2 = n2;
    }
    const float gs = m1 + m2;       // identical on all 8 lanes of the group
    const int   g  = lane >> 3;

    // ---- top-4 groups (ties -> lower group index) ----
    int rank = 0;
#pragma unroll
    for (int gg = 0; gg < 8; ++gg) {
        const float og = __shfl(gs, gg * 8);
        rank += (og > gs) || (og == gs && gg < g);
    }
    const bool gsel = rank < 4;

    // ---- candidates: masked_scores = scores_for_choice * group_mask (exact 0.0f) ----
    float v[4];
#pragma unroll
    for (int j = 0; j < 4; ++j) v[j] = gsel ? c[j] : 0.0f;

    // ---- 8 iterative argmax extractions (descending, ties -> lower index) ----
    float selw = 0.f;   // raw sigmoid score of the winner at iteration == lane
    int   seli = 0;
    float wsum = 0.f;

#pragma unroll
    for (int k = 0; k < 8; ++k) {
        // lane-local best (strict > keeps lowest index on ties)
        float bvv = v[0]; int bi = lane * 4; float br = s[0];
#pragma unroll
        for (int j = 1; j < 4; ++j) {
            if (v[j] > bvv) { bvv = v[j]; bi = lane * 4 + j; br = s[j]; }
        }
        // wave-wide reduce
#pragma unroll
        for (int off = 32; off > 0; off >>= 1) {
            const float ov = __shfl_xor(bvv, off);
            const int   oi = __shfl_xor(bi, off);
            const float orr = __shfl_xor(br, off);
            if (ov > bvv || (ov == bvv && oi < bi)) { bvv = ov; bi = oi; br = orr; }
        }
        if (lane == k) { selw = br; seli = bi; }
        wsum += br;
        // remove winner from its owner lane (static indices only)
        const int rem = bi - lane * 4;
#pragma unroll
        for (int j = 0; j < 4; ++j)
            if (rem == j) v[j] = -INFINITY;
    }

    if (lane < 8) {
        const float w = selw / (wsum + 1e-20f) * 2.5f;
        out_w[(size_t)t * 8 + lane] = w;
        out_e[(size_t)t * 8 + lane] = (float)seli;   // harness reads as float
    }
}

extern "C" void kernel_launch(void* const* d_in, const int* in_sizes, int n_in,
                              void* d_out, int out_size, void* d_ws, size_t ws_size,
                              hipStream_t stream) {
    const float* X    = (const float*)d_in[0];   // [8192,7168]
    const float* W    = (const float*)d_in[1];   // [256,7168]
    const float* bias = (const float*)d_in[2];   // [256]
    float* out    = (float*)d_out;               // [8192*8] weights, then [8192*8] indices
    float* logits = (float*)d_ws;                // 8192*256*4 = 8 MB scratch

    dim3 ggrid(T_TOK / BM, NEXP / BN);           // 64 x 4 = 256 blocks
    router_gemm<<<ggrid, 256, 0, stream>>>(X, W, logits);

    gate_kernel<<<T_TOK / 4, 256, 0, stream>>>(logits, bias, out, out + (size_t)T_TOK * 8);
}